// Round 6
// baseline (226.728 us; speedup 1.0000x reference)
//
#include <hip/hip_runtime.h>
#include <hip/hip_bf16.h>
#include <math.h>

typedef unsigned long long u64;

// ===========================================================================
// k_prep: ONE kernel for all parameter preprocessing.
//   region 0: wave-per-word sign pack, 7 segments:
//             5 psum stages -> combined wlut (stride-4: {w0,w1,dp,dn}),
//             fc2 -> transposed [16][1024], fc3 -> plain [10][16]
//   region 1: fc1 pack -> transposed [128][1024] with channel-major bit layout
//   region 2: LSQ delta LUT {dp,dn} into wlut slots 2,3 (exact f64, reference
//             expression order; saturation of |isum|>=2 guaranteed by alpha
//             range: |(+-2+b)/a| >= 13 >> 4.5)
//   region 3: CZ[o] = sum_s cz(s,o) in ascending-s order (exact f64)
// ===========================================================================
struct PrepArgs {
    const float* w[7];
    u64* out[7];
    int cnt[7];     // words per segment
    int mode[7];    // 0 plain, 1 stage-combined (idx=(li>>1)*4+(li&1)), 2 fc2T
    const float* fc1w;
    u64* fc1T;
    const float* alpha[5];
    const float* bias[5];
    int loff[5];    // prefix row offsets {0,1152,3456,8064,17280}
    int lCout[5];
    double gq[5];   // 1/sqrt(ysize*3)
    u64* wlut;
    double* czv;
    int czoff[5];   // {0,128,384,640,1152}
    int czS[5];
    int R1, R2, R3, R4;   // region thread boundaries
};

__global__ __launch_bounds__(256)
void k_prep(PrepArgs A) {
    int gid = blockIdx.x * 256 + threadIdx.x;
    int lane = threadIdx.x & 63;
    if (gid < A.R1) {
        // ---- generic wave-per-word pack ----
        int wid = gid >> 6;
        int seg = 0, base = 0, pre = 0;
#pragma unroll
        for (int t = 0; t < 7; ++t) {
            if (wid >= pre) { seg = t; base = pre; }
            pre += A.cnt[t];
        }
        int li = wid - base;
        const float* p = A.w[seg] + ((size_t)li << 6);
        u64 m = __ballot(p[lane] > 0.f);
        if (lane == 0) {
            int mode = A.mode[seg];
            size_t idx = (mode == 1) ? ((size_t)(li >> 1) * 4 + (li & 1))
                       : (mode == 2) ? ((size_t)(li & 15) * 1024 + (li >> 4))
                       : (size_t)li;
            A.out[seg][idx] = m;
        }
    } else if (gid < A.R2) {
        // ---- fc1 pack (channel-major bit layout, transposed output) ----
        int wid = (gid - A.R1) >> 6;
        int row = wid >> 3, gk = wid & 7;
        int g = gk >> 1, k = gk & 1;
        int c = g * 128 + k * 64 + lane;
        const float* p = A.fc1w + (size_t)row * 8192 + (size_t)c * 16;
        float arr[16];
#pragma unroll
        for (int q = 0; q < 4; ++q) {
            float4 f = ((const float4*)p)[q];
            arr[4 * q + 0] = f.x; arr[4 * q + 1] = f.y;
            arr[4 * q + 2] = f.z; arr[4 * q + 3] = f.w;
        }
#pragma unroll
        for (int h = 0; h < 4; ++h)
#pragma unroll
        for (int xq = 0; xq < 4; ++xq) {
            u64 m = __ballot(arr[h * 4 + xq] > 0.f);
            if (lane == 0) {
                int wd = g * 32 + h * 8 + xq * 2 + k;
                A.fc1T[(size_t)wd * 1024 + row] = m;
            }
        }
    } else if (gid < A.R3) {
        // ---- LSQ delta LUT ----
        int idx = gid - A.R2;
        int seg = 0;
#pragma unroll
        for (int t = 1; t < 5; ++t) if (idx >= A.loff[t]) seg = t;
        int li = idx - A.loff[seg];
        int s = li / A.lCout[seg];
        double al = (double)A.alpha[seg][s];
        double tg = al * A.gq[seg];
        double a  = tg + (al - tg);
        double b  = (double)A.bias[seg][li];
        double q0 = rint(fmin(fmax(b / a, -4.0), 3.0));
        double qp = rint(fmin(fmax((2.0 + b) / a, -4.0), 3.0));
        double qn = rint(fmin(fmax((-2.0 + b) / a, -4.0), 3.0));
        double cz = q0 * a;
        A.wlut[(size_t)idx * 4 + 2] = __double_as_longlong(qp * a - cz);
        A.wlut[(size_t)idx * 4 + 3] = __double_as_longlong(qn * a - cz);
    } else if (gid < A.R4) {
        // ---- CZ per (stage, o) ----
        int idx = gid - A.R3;
        int seg = 0;
#pragma unroll
        for (int t = 1; t < 5; ++t) if (idx >= A.czoff[t]) seg = t;
        int o = idx - A.czoff[seg];
        int Cout = A.lCout[seg];
        double CZ = 0.0;
        for (int s = 0; s < A.czS[seg]; ++s) {
            double al = (double)A.alpha[seg][s];
            double tg = al * A.gq[seg];
            double a  = tg + (al - tg);
            double b  = (double)A.bias[seg][s * Cout + o];
            double q0 = rint(fmin(fmax(b / a, -4.0), 3.0));
            CZ += q0 * a;
        }
        A.czv[idx] = CZ;
    }
}

// ===========================================================================
// conv1 (3->128, 3x3, pad 1) + bias + bn1 affine -> packed sign bits.
// Block = (b,row), 128 threads = channels; rolling accumulators over cols.
// ===========================================================================
__global__ __launch_bounds__(128)
void k_conv1(const float* __restrict__ x, const float* __restrict__ w,
             const float* __restrict__ cb, const float* __restrict__ g1,
             const float* __restrict__ b1, u64* __restrict__ apack) {
    __shared__ double xs[3][3][34];        // [ky][ci][paddedcol]
    int h = blockIdx.x & 31;
    int b = blockIdx.x >> 5;
    int tid = threadIdx.x;
    for (int idx = tid; idx < 306; idx += 128) {
        int dyy = idx / 102;
        int rem = idx - dyy * 102;
        int ci = rem / 34;
        int col = rem - ci * 34;
        int y = h + dyy - 1, xx = col - 1;
        double v = 0.0;
        if ((unsigned)y < 32u && (unsigned)xx < 32u)
            v = (double)x[((b * 3 + ci) * 32 + y) * 32 + xx];
        xs[dyy][ci][col] = v;
    }
    __syncthreads();
    int o = tid;
    double sg[3][3][3];   // [kx][ci][ky]
#pragma unroll
    for (int ci = 0; ci < 3; ++ci)
#pragma unroll
    for (int ky = 0; ky < 3; ++ky)
#pragma unroll
    for (int kx = 0; kx < 3; ++kx) {
        float wv = w[o * 27 + (ci * 3 + ky) * 3 + kx];
        sg[kx][ci][ky] = wv > 0.f ? 1.0 : (wv < 0.f ? -1.0 : 0.0);
    }
    double cbv = (double)cb[o], g1v = (double)g1[o], b1v = (double)b1[o];
    double A0 = 0.0, A1 = 0.0, A2 = 0.0;
    for (int pc = 0; pc < 34; ++pc) {
        double v[3][3];
#pragma unroll
        for (int ky = 0; ky < 3; ++ky)
#pragma unroll
        for (int ci = 0; ci < 3; ++ci)
            v[ky][ci] = xs[ky][ci][pc];
        A2 = 0.0;
#pragma unroll
        for (int ci = 0; ci < 3; ++ci)
#pragma unroll
        for (int ky = 0; ky < 3; ++ky) {
            A0 += v[ky][ci] * sg[2][ci][ky];
            A1 += v[ky][ci] * sg[1][ci][ky];
            A2 += v[ky][ci] * sg[0][ci][ky];
        }
        if (pc >= 2) {
            int wc = pc - 2;
            double t = (A0 + cbv) * g1v + b1v;
            u64 m = __ballot(t > 0.0);
            if ((tid & 63) == 0)
                apack[((size_t)(b * 1024 + h * 32 + wc)) * 2 + (tid >> 6)] = m;
        }
        A0 = A1; A1 = A2;
    }
}

// ===========================================================================
// Fused psum-stage + (2x2 maxpool) + BN affine + sign-pack, register version.
// Thread = (b, o, one RAW row yr, 8-col chunk). Per (g,i): activation row is
// loaded ONCE into registers (wave-uniform address -> one broadcast L2 access
// per word), then j=0..2 sweep 8 cols from registers. Table {w0,w1,dp,dn}
// loaded once per slice, amortized over 24 positions. No LDS in the main
// loop. Pool combines row pairs via small LDS exchange.
// Delta order is (g,i,j) vs reference (g,j,i): f64 reorder, err ~1e-14.
// ===========================================================================
template <int POOL, int G, int H, int W, int Cout, int RCH, int NCH>
__global__ __launch_bounds__(64 * RCH * NCH)
void k_stage(const u64* __restrict__ apack, const u64* __restrict__ wlut,
             const double* __restrict__ czv,
             const float* __restrict__ gam, const float* __restrict__ bet,
             u64* __restrict__ opack) {
    constexpr int CW = W / NCH;            // raw cols per thread (8 everywhere)
    constexpr int Ho = H / POOL, Wo = W / POOL;
    constexpr int NOC = Cout / 64;
    constexpr int NRB = H / RCH;

    int bi = blockIdx.x;
    int och = bi % NOC; bi /= NOC;
    int rb = bi % NRB;
    int b = bi / NRB;
    int tid = threadIdx.x;
    int ol = tid & 63;
    int rr = tid >> 6;                     // wave-uniform
    int rc = rr / NCH;
    int nc = rr - rc * NCH;
    int o = och * 64 + ol;
    int yr = rb * RCH + rc;

    double CZ = czv[o];
    double acc[CW];
#pragma unroll
    for (int c = 0; c < CW; ++c) acc[c] = CZ;

    ulonglong2 ar[CW + 2];                 // padded activation row (registers)

    for (int g = 0; g < G; ++g) {
#pragma unroll
        for (int i = 0; i < 3; ++i) {
            int y = yr + i - 1;
            if ((unsigned)y >= (unsigned)H) continue;   // pad row: cz, in CZ
            const ulonglong2* rp = (const ulonglong2*)
                (apack + ((((size_t)(b * G + g) * H + y) * W + nc * CW - 1)) * 2);
#pragma unroll
            for (int k = 0; k < CW + 2; ++k) {
                if ((k > 0 || nc > 0) && (k < CW + 1 || nc < NCH - 1))
                    ar[k] = rp[k];
            }
#pragma unroll
            for (int j = 0; j < 3; ++j) {
                const int s = g * 9 + j * 3 + i;
                size_t so = (size_t)s * Cout + o;
                ulonglong2 wv = *(const ulonglong2*)(wlut + so * 4);
                ulonglong2 dv = *(const ulonglong2*)(wlut + so * 4 + 2);
                u64 w0 = wv.x, w1 = wv.y;
                double dp = __longlong_as_double(dv.x);
                double dn = __longlong_as_double(dv.y);
#pragma unroll
                for (int c = 0; c < CW; ++c) {
                    if (c == 0 && j == 0 && nc == 0) continue;             // pad col
                    if (c == CW - 1 && j == 2 && nc == NCH - 1) continue;  // pad col
                    u64 a0 = ar[c + j].x, a1 = ar[c + j].y;
                    int d = __popcll(a0 ^ w0) + __popcll(a1 ^ w1);
                    double val = (d < 64) ? dp : dn;
                    val = (d == 64) ? 0.0 : val;
                    acc[c] += val;
                }
            }
        }
    }

    double gv = (double)gam[o], bv = (double)bet[o];
    if constexpr (POOL == 1) {
#pragma unroll
        for (int c = 0; c < CW; ++c) {
            double t = acc[c] * gv + bv;
            u64 bm = __ballot(t > 0.0);
            if (ol == 0) {
                int pw = nc * CW + c;
                opack[(((size_t)(b * (Cout >> 7) + (o >> 7)) * Ho + yr) * Wo + pw) * 2
                      + (och & 1)] = bm;
            }
        }
    } else {
        __shared__ double pl[RCH / 2][NCH][CW / 2][64];
        double m2[CW / 2];
#pragma unroll
        for (int c2 = 0; c2 < CW / 2; ++c2)
            m2[c2] = fmax(acc[2 * c2], acc[2 * c2 + 1]);
        if (rc & 1) {
#pragma unroll
            for (int c2 = 0; c2 < CW / 2; ++c2)
                pl[rc >> 1][nc][c2][ol] = m2[c2];
        }
        __syncthreads();
        if (!(rc & 1)) {
#pragma unroll
            for (int c2 = 0; c2 < CW / 2; ++c2) {
                double m = fmax(m2[c2], pl[rc >> 1][nc][c2][ol]);
                double t = m * gv + bv;
                u64 bm = __ballot(t > 0.0);
                if (ol == 0) {
                    int ph = yr >> 1;
                    int pw = ((nc * CW) >> 1) + c2;
                    opack[(((size_t)(b * (Cout >> 7) + (o >> 7)) * Ho + ph) * Wo + pw) * 2
                          + (och & 1)] = bm;
                }
            }
        }
    }
}

// ===========================================================================
// Whole classifier in one kernel: block = one batch image (1024 threads).
// ===========================================================================
__global__ __launch_bounds__(1024)
void k_fc_all(const u64* __restrict__ abits, const u64* __restrict__ wf1T,
              const float* __restrict__ b1, const float* __restrict__ g1,
              const float* __restrict__ a1,
              const u64* __restrict__ wf2T,
              const float* __restrict__ b2, const float* __restrict__ g2,
              const float* __restrict__ a2,
              const u64* __restrict__ wf3,
              const float* __restrict__ b3, const float* __restrict__ g3,
              const float* __restrict__ a3,
              float* __restrict__ out) {
    __shared__ u64 sa[128];
    __shared__ u64 sp1[16];
    __shared__ u64 sp2[16];
    int b = blockIdx.x;
    int t = threadIdx.x;
    if (t < 128) sa[t] = abits[(size_t)b * 128 + t];
    __syncthreads();
    {
        int d = 0;
#pragma unroll 16
        for (int i = 0; i < 128; ++i)
            d += __popcll(sa[i] ^ wf1T[(size_t)i * 1024 + t]);
        double isum = (double)(8192 - 2 * d);
        double v = (isum + (double)b1[t]) * (double)g1[t] + (double)a1[t];
        u64 m = __ballot(v > 0.0);
        if ((t & 63) == 0) sp1[t >> 6] = m;
    }
    __syncthreads();
    {
        int d = 0;
#pragma unroll
        for (int i = 0; i < 16; ++i)
            d += __popcll(sp1[i] ^ wf2T[(size_t)i * 1024 + t]);
        double isum = (double)(1024 - 2 * d);
        double v = (isum + (double)b2[t]) * (double)g2[t] + (double)a2[t];
        u64 m = __ballot(v > 0.0);
        if ((t & 63) == 0) sp2[t >> 6] = m;
    }
    __syncthreads();
    if (t < 10) {
        int d = 0;
#pragma unroll
        for (int i = 0; i < 16; ++i)
            d += __popcll(sp2[i] ^ wf3[t * 16 + i]);
        double isum = (double)(1024 - 2 * d);
        out[b * 10 + t] = (float)((isum + (double)b3[t]) * (double)g3[t] + (double)a3[t]);
    }
}

// ===========================================================================

extern "C" void kernel_launch(void* const* d_in, const int* in_sizes, int n_in,
                              void* d_out, int out_size, void* d_ws, size_t ws_size,
                              hipStream_t stream) {
    const float* x       = (const float*)d_in[0];
    const float* conv1_w = (const float*)d_in[1];
    const float* conv1_b = (const float*)d_in[2];
    const float* s_w[5]  = {(const float*)d_in[3], (const float*)d_in[6], (const float*)d_in[9],
                            (const float*)d_in[12], (const float*)d_in[15]};
    const float* s_b[5]  = {(const float*)d_in[4], (const float*)d_in[7], (const float*)d_in[10],
                            (const float*)d_in[13], (const float*)d_in[16]};
    const float* s_a[5]  = {(const float*)d_in[5], (const float*)d_in[8], (const float*)d_in[11],
                            (const float*)d_in[14], (const float*)d_in[17]};
    const float* bn_g[6], *bn_b[6];
    for (int i = 0; i < 6; ++i) { bn_g[i] = (const float*)d_in[18 + 2 * i]; bn_b[i] = (const float*)d_in[19 + 2 * i]; }
    const float* fc1_w = (const float*)d_in[30]; const float* fc1_b = (const float*)d_in[31];
    const float* fc2_w = (const float*)d_in[32]; const float* fc2_b = (const float*)d_in[33];
    const float* fc3_w = (const float*)d_in[34]; const float* fc3_b = (const float*)d_in[35];
    const float* fbn_g[3], *fbn_b[3];
    for (int i = 0; i < 3; ++i) { fbn_g[i] = (const float*)d_in[36 + 2 * i]; fbn_b[i] = (const float*)d_in[37 + 2 * i]; }

    // ---- workspace carve-up -------------------------------------------------
    size_t off = 0;
    auto alloc = [&](size_t bytes) { off = (off + 255) & ~(size_t)255; size_t o = off; off += bytes; return o; };
    char* ws = (char*)d_ws;
    size_t o_apA  = alloc(1048576);
    size_t o_apB  = alloc(1048576);
    size_t o_wlut = alloc((size_t)35712 * 4 * 8);     // {w0,w1,dp,dn} per (s,o)
    size_t o_cz   = alloc((size_t)1664 * 8);
    size_t o_wf1  = alloc((size_t)1024 * 128 * 8);    // fc1 transposed
    size_t o_wf2  = alloc((size_t)1024 * 16 * 8);     // fc2 transposed
    size_t o_wf3  = alloc((size_t)160 * 8);
    if (off > ws_size) return;

    u64* apA = (u64*)(ws + o_apA);
    u64* apB = (u64*)(ws + o_apB);
    u64* wlut = (u64*)(ws + o_wlut);
    double* czbuf = (double*)(ws + o_cz);
    u64* wf1T = (u64*)(ws + o_wf1);
    u64* wf2T = (u64*)(ws + o_wf2);
    u64* wf3 = (u64*)(ws + o_wf3);

    const int rowoff[5] = {0, 1152, 3456, 8064, 17280};
    const int czoff[5]  = {0, 128, 384, 640, 1152};
    const int sS[5]     = {9, 9, 18, 18, 36};
    const int sCout[5]  = {128, 256, 256, 512, 512};
    const double sYsz[5] = {8388608.0, 4194304.0, 4194304.0, 2097152.0, 2097152.0};

    // ---- one prep kernel ---------------------------------------------------
    PrepArgs PA;
    const int scnt[5] = {2304, 4608, 9216, 18432, 36864};   // words (rows*2)
    int totw = 0;
    for (int i = 0; i < 5; ++i) {
        PA.w[i] = s_w[i];
        PA.out[i] = wlut + (size_t)rowoff[i] * 4;
        PA.cnt[i] = scnt[i];
        PA.mode[i] = 1;
        totw += scnt[i];
    }
    PA.w[5] = fc2_w; PA.out[5] = wf2T; PA.cnt[5] = 1024 * 16; PA.mode[5] = 2; totw += 1024 * 16;
    PA.w[6] = fc3_w; PA.out[6] = wf3;  PA.cnt[6] = 160;       PA.mode[6] = 0; totw += 160;
    PA.fc1w = fc1_w; PA.fc1T = wf1T;
    for (int i = 0; i < 5; ++i) {
        PA.alpha[i] = s_a[i]; PA.bias[i] = s_b[i];
        PA.loff[i] = rowoff[i]; PA.lCout[i] = sCout[i];
        PA.gq[i] = 1.0 / sqrt(sYsz[i] * 3.0);
        PA.czoff[i] = czoff[i]; PA.czS[i] = sS[i];
    }
    PA.wlut = wlut; PA.czv = czbuf;
    PA.R1 = totw * 64;
    PA.R2 = PA.R1 + 1024 * 8 * 64;
    PA.R3 = PA.R2 + 35712;
    PA.R4 = PA.R3 + 1664;
    k_prep<<<(PA.R4 + 255) / 256, 256, 0, stream>>>(PA);

    // ---- conv1 + bn1 -> signs (apA: [64][1][32][32][2]) --------------------
    k_conv1<<<64 * 32, 128, 0, stream>>>(x, conv1_w, conv1_b, bn_g[0], bn_b[0], apA);

    // ---- fused stages (register-based, 2048 blocks each) -------------------
    //        POOL G  H   W  Cout RCH NCH         grid = B * (H/RCH) * (Cout/64)
    k_stage<2, 1, 32, 32, 128, 2, 4><<<64 * 16 * 2, 512, 0, stream>>>(
        apA, wlut + (size_t)rowoff[0] * 4, czbuf + czoff[0], bn_g[1], bn_b[1], apB);
    k_stage<1, 1, 16, 16, 256, 2, 2><<<64 * 8 * 4, 256, 0, stream>>>(
        apB, wlut + (size_t)rowoff[1] * 4, czbuf + czoff[1], bn_g[2], bn_b[2], apA);
    k_stage<2, 2, 16, 16, 256, 2, 2><<<64 * 8 * 4, 256, 0, stream>>>(
        apA, wlut + (size_t)rowoff[2] * 4, czbuf + czoff[2], bn_g[3], bn_b[3], apB);
    k_stage<1, 2, 8, 8, 512, 2, 1><<<64 * 4 * 8, 128, 0, stream>>>(
        apB, wlut + (size_t)rowoff[3] * 4, czbuf + czoff[3], bn_g[4], bn_b[4], apA);
    k_stage<2, 4, 8, 8, 512, 2, 1><<<64 * 4 * 8, 128, 0, stream>>>(
        apA, wlut + (size_t)rowoff[4] * 4, czbuf + czoff[4], bn_g[5], bn_b[5], apB);

    // ---- classifier (one kernel) -------------------------------------------
    k_fc_all<<<64, 1024, 0, stream>>>(apB, wf1T, fc1_b, fbn_g[0], fbn_b[0],
                                      wf2T, fc2_b, fbn_g[1], fbn_b[1],
                                      wf3, fc3_b, fbn_g[2], fbn_b[2],
                                      (float*)d_out);
}